// Round 1
// baseline (8396.291 us; speedup 1.0000x reference)
//
#include <hip/hip_runtime.h>

typedef float f32x4  __attribute__((ext_vector_type(4)));
typedef float f32x16 __attribute__((ext_vector_type(16)));
typedef short short8 __attribute__((ext_vector_type(8)));

#define TT 1024
#define DD 512
#define BTD (32u*1024u*512u)

__device__ __forceinline__ unsigned short f2bf(float f){
  unsigned int u = __float_as_uint(f);
  u += 0x7FFFu + ((u >> 16) & 1u);          // round-to-nearest-even
  return (unsigned short)(u >> 16);
}
__device__ __forceinline__ float fast_tanh(float x){
  float ax = fabsf(x);
  float e  = __expf(2.0f*ax);
  float r  = 1.0f - 2.0f/(e + 1.0f);
  return x < 0.f ? -r : r;
}

// ---------------- prep: hd -> bf16 ----------------
__global__ void prep_hd_k(const float* __restrict__ hd, unsigned short* __restrict__ out){
  const unsigned n4 = 16777216u/4u;
  for (unsigned i = blockIdx.x*blockDim.x + threadIdx.x; i < n4; i += gridDim.x*blockDim.x){
    f32x4 v = *reinterpret_cast<const f32x4*>(hd + 4u*(size_t)i);
    uint2 o;
    o.x = (unsigned)f2bf(v[0]) | ((unsigned)f2bf(v[1])<<16);
    o.y = (unsigned)f2bf(v[2]) | ((unsigned)f2bf(v[3])<<16);
    *reinterpret_cast<uint2*>(out + 4u*(size_t)i) = o;
  }
}

// ---------------- prep: z, packed weights, d_init, flags ----------------
__global__ void prep_misc_k(const float* __restrict__ A, const float* __restrict__ noise,
                            const float* __restrict__ Wd, const float* __restrict__ Wz,
                            const float* __restrict__ Wdz, const float* __restrict__ Whd,
                            const float* __restrict__ init_h,
                            unsigned short* __restrict__ zbf, unsigned short* __restrict__ Wu,
                            unsigned short* __restrict__ Wp, unsigned short* __restrict__ dcomm,
                            int* __restrict__ flags){
  const unsigned NZ = 2097152u, NWU = 294912u, NWP = 327680u, ND = 16384u;
  const unsigned NT = NZ + NWU + NWP + ND + 32u;
  for (unsigned i = blockIdx.x*blockDim.x + threadIdx.x; i < NT; i += gridDim.x*blockDim.x){
    if (i < NZ){                                   // z = tanh(mu_in_q) + noise*exp(ln_q)
      unsigned m = i >> 6, zi = i & 63u;
      float muin = A[(size_t)m*128u + zi];
      float ln   = A[(size_t)m*128u + 64u + zi];
      zbf[i] = f2bf(fast_tanh(muin) + noise[i]*__expf(ln));
    } else if (i < NZ+NWU){                        // Wu[c][kk]: [Whd | Wz], [512][576]
      unsigned j = i - NZ;
      unsigned c = j / 576u, kk = j - c*576u;
      float v = (kk < 512u) ? Whd[(size_t)c*512u + kk] : Wz[(size_t)c*64u + (kk-512u)];
      Wu[j] = f2bf(v);
    } else if (i < NZ+NWU+NWP){                    // Wp[c][k]: [Wd | Wdz interleaved], [640][512]
      unsigned j = i - (NZ+NWU);
      unsigned c = j >> 9, k = j & 511u;
      float v;
      if (c < 512u) v = Wd[(size_t)c*512u + k];
      else {
        unsigned jj = c - 512u, g = jj >> 5, w = jj & 31u;
        unsigned z = g*16u + (w & 15u), half = w >> 4;
        v = Wdz[(size_t)(half*64u + z)*512u + k];
      }
      Wp[j] = f2bf(v);
    } else if (i < NZ+NWU+NWP+ND){                 // d_{-1} = tanh(init_h) into slot 1
      unsigned j = i - (NZ+NWU+NWP);
      dcomm[16384u + j] = f2bf(fast_tanh(init_h[j]));
    } else {
      unsigned j = i - (NZ+NWU+NWP+ND);
      if (j < 20u) flags[j] = 0;
    }
  }
}

// ---------------- wnll_init_h -> d_out[BTD] ----------------
__global__ void wnll_k(const float* __restrict__ init_h, const float* __restrict__ mu,
                       float* __restrict__ dout){
  __shared__ float red[256];
  float s = 0.f;
  for (unsigned i = threadIdx.x; i < 16384u; i += 256u){
    float x = init_h[i] - mu[i & 511u];
    s += 0.5f*x*x;
  }
  red[threadIdx.x] = s; __syncthreads();
  for (int st = 128; st > 0; st >>= 1){
    if ((int)threadIdx.x < st) red[threadIdx.x] += red[threadIdx.x + st];
    __syncthreads();
  }
  if (threadIdx.x == 0){
    float nll = (red[0] + 16384.0f*0.91893853320467274f) / 512.0f;
    dout[(size_t)BTD] = 1e-3f * nll;
  }
}

// ---------------- U = (X @ Wu^T + bias)/tau  into d_out ----------------
__global__ __launch_bounds__(256) void gemm_u_k(
    const unsigned short* __restrict__ Xhd,   // [32768][512] bf16
    const unsigned short* __restrict__ Xz,    // [32768][64]  bf16
    const unsigned short* __restrict__ Wu,    // [512][576]   bf16
    const float* __restrict__ bias,
    float* __restrict__ dout)                 // [32768][512] f32
{
  __shared__ __align__(16) unsigned short Xs[128][40];   // 128m x 32k (+8 pad)
  __shared__ __align__(16) unsigned short Ws[128][40];   // 128c x 32k
  const int bm = blockIdx.x >> 2;
  const int bn = blockIdx.x & 3;
  const int tid = threadIdx.x;
  const int lane = tid & 63;
  const int wv = tid >> 6;
  const int m0 = (wv >> 1) * 64, c0 = (wv & 1) * 64;
  f32x4 acc[4][4];
  #pragma unroll
  for (int i=0;i<4;++i)
    #pragma unroll
    for (int j=0;j<4;++j)
      #pragma unroll
      for (int r=0;r<4;++r) acc[i][j][r] = 0.f;

  const int sm = tid >> 1;
  const int sk = (tid & 1) * 16;
  for (int kt = 0; kt < 18; ++kt){
    __syncthreads();
    {
      int mg = bm*128 + sm;
      const unsigned short* src = (kt < 16)
          ? (Xhd + (size_t)mg*512u + (unsigned)(kt*32 + sk))
          : (Xz  + (size_t)mg*64u  + (unsigned)((kt-16)*32 + sk));
      uint4 v0 = *reinterpret_cast<const uint4*>(src);
      uint4 v1 = *reinterpret_cast<const uint4*>(src + 8);
      *reinterpret_cast<uint4*>(&Xs[sm][sk])   = v0;
      *reinterpret_cast<uint4*>(&Xs[sm][sk+8]) = v1;
      int cg = bn*128 + sm;
      const unsigned short* wsrc = Wu + (size_t)cg*576u + (unsigned)(kt*32 + sk);
      uint4 w0 = *reinterpret_cast<const uint4*>(wsrc);
      uint4 w1 = *reinterpret_cast<const uint4*>(wsrc + 8);
      *reinterpret_cast<uint4*>(&Ws[sm][sk])   = w0;
      *reinterpret_cast<uint4*>(&Ws[sm][sk+8]) = w1;
    }
    __syncthreads();
    short8 af[4], bf[4];
    #pragma unroll
    for (int i=0;i<4;++i)
      af[i] = *reinterpret_cast<const short8*>(&Xs[m0 + i*16 + (lane&15)][(lane>>4)*8]);
    #pragma unroll
    for (int j=0;j<4;++j)
      bf[j] = *reinterpret_cast<const short8*>(&Ws[c0 + j*16 + (lane&15)][(lane>>4)*8]);
    #pragma unroll
    for (int i=0;i<4;++i)
      #pragma unroll
      for (int j=0;j<4;++j)
        acc[i][j] = __builtin_amdgcn_mfma_f32_16x16x32_bf16(af[i], bf[j], acc[i][j], 0, 0, 0);
  }
  #pragma unroll
  for (int j=0;j<4;++j){
    int cg = bn*128 + c0 + j*16 + (lane&15);
    float bia  = bias[cg];
    float itau = (cg < 256) ? 0.25f : 0.5f;
    #pragma unroll
    for (int i=0;i<4;++i){
      int mbase = bm*128 + m0 + i*16 + (lane>>4)*4;
      #pragma unroll
      for (int r=0;r<4;++r)
        dout[(size_t)(mbase + r)*512u + cg] = (acc[i][j][r] + bia) * itau;
    }
  }
}

// ---------------- persistent serial recurrence: 20 WGs x 1 wave ----------------
// WG 0..15: D columns [32*wg, 32*wg+32);  WG 16..19: prior columns + KL.
__global__ __launch_bounds__(64,1) void recur_k(
    float* __restrict__ dout, const float* __restrict__ A, const float* __restrict__ init_h,
    const unsigned short* __restrict__ Wp, unsigned short* __restrict__ dcomm,
    int* __restrict__ flags)
{
  const int wg   = blockIdx.x;
  const int lane = threadIdx.x;
  const bool isKL = (wg >= 16);
  const int col   = wg*32 + (lane & 31);      // packed column (0..639)
  const int khalf = (lane >> 5) * 8;          // k sub-offset of this lane half
  const int bof   = (lane >> 5) * 4;          // row offset in C-layout

  // weights resident in VGPRs: 32 fragments of 8 bf16
  short8 wfrag[32];
  #pragma unroll
  for (int kc = 0; kc < 32; ++kc)
    wfrag[kc] = *reinterpret_cast<const short8*>(Wp + (size_t)col*512u + (unsigned)(kc*16 + khalf));

  const float dec  = (col < 256) ? 0.75f : 0.5f;
  const float itau = (col < 256) ? 0.25f : 0.5f;

  float h[16];
  if (!isKL){
    #pragma unroll
    for (int r=0;r<16;++r){
      int b = (r&3) + 8*(r>>2) + bof;
      h[r] = init_h[b*512 + col];
    }
  }
  const int  zidx   = (wg - 16)*16 + (lane & 15);
  const bool muLane = ((lane & 16) == 0);
  float kacc = 0.f;

  for (int t = 0; t < TT; ++t){
    // prefetch recurrence-independent data (U slice / posterior params)
    float u[16], aqm[16], aql[16];
    if (!isKL){
      #pragma unroll
      for (int r=0;r<16;++r){
        int b = (r&3) + 8*(r>>2) + bof;
        u[r] = dout[((size_t)b*TT + t)*DD + col];
      }
    } else {
      #pragma unroll
      for (int r=0;r<16;++r){
        int b = (r&3) + 8*(r>>2) + bof;
        const float* ap = A + ((size_t)b*TT + t)*128u;
        aqm[r] = ap[zidx]; aql[r] = ap[64 + zidx];
      }
    }
    // lockstep: wait until every WG finished step t-1
    if (t > 0){
      for (;;){
        int ok = 1;
        if (lane < 20)
          ok = (__hip_atomic_load(&flags[lane], __ATOMIC_RELAXED, __HIP_MEMORY_SCOPE_AGENT) >= t);
        if (__all(ok)) break;
      }
      __builtin_amdgcn_fence(__ATOMIC_ACQUIRE, "agent");
    }
    // P = d_{t-1} @ W_slice   (two interleaved MFMA chains)
    const unsigned short* ds = dcomm + ((t-1)&1)*16384 + (lane&31)*512 + khalf;
    f32x16 acc0, acc1;
    #pragma unroll
    for (int q=0;q<16;++q){ acc0[q]=0.f; acc1[q]=0.f; }
    #pragma unroll
    for (int kc=0;kc<16;++kc){
      short8 a0 = *reinterpret_cast<const short8*>(ds + (2*kc  )*16);
      short8 a1 = *reinterpret_cast<const short8*>(ds + (2*kc+1)*16);
      acc0 = __builtin_amdgcn_mfma_f32_32x32x16_bf16(a0, wfrag[2*kc  ], acc0, 0, 0, 0);
      acc1 = __builtin_amdgcn_mfma_f32_32x32x16_bf16(a1, wfrag[2*kc+1], acc1, 0, 0, 0);
    }
    if (!isKL){
      float dv[16];
      #pragma unroll
      for (int r=0;r<16;++r){
        float P = acc0[r] + acc1[r];
        h[r]  = dec*h[r] + P*itau + u[r];
        dv[r] = fast_tanh(h[r]);
      }
      // d_seq (agent-coherent stores: no dirty L2 lines in this kernel)
      #pragma unroll
      for (int r=0;r<16;++r){
        int b = (r&3) + 8*(r>>2) + bof;
        __hip_atomic_store(&dout[((size_t)b*TT + t)*DD + col], dv[r],
                           __ATOMIC_RELAXED, __HIP_MEMORY_SCOPE_AGENT);
      }
      // bf16 d_comm, paired dword stores
      unsigned short* dslot = dcomm + (t&1)*16384;
      #pragma unroll
      for (int r=0;r<16;++r){
        float nb = __shfl_xor(dv[r], 1, 64);
        unsigned short mb = f2bf(dv[r]), ob = f2bf(nb);
        unsigned int dw = (lane & 1) ? (((unsigned)mb<<16) | ob) : (((unsigned)ob<<16) | mb);
        if ((lane & 1) == ((r < 8) ? 0 : 1)){
          int b = (r&3) + 8*(r>>2) + bof;
          unsigned int* dst = reinterpret_cast<unsigned int*>(dslot + b*512 + (col & ~1));
          __hip_atomic_store(dst, dw, __ATOMIC_RELAXED, __HIP_MEMORY_SCOPE_AGENT);
        }
      }
      if (lane == 0)
        __hip_atomic_store(&flags[wg], t+1, __ATOMIC_RELEASE, __HIP_MEMORY_SCOPE_AGENT);
    } else {
      // prior + KL
      #pragma unroll
      for (int r=0;r<16;++r){
        float P = acc0[r] + acc1[r];
        if (t == 0) P = 0.f;                       // in_p0 is zeros
        float other = __shfl_xor(P, 16, 64);       // pair mu <-> ln lanes
        if (muLane){
          float mu_p  = fast_tanh(P);
          float sig_p = __expf(other);
          float mu_q  = fast_tanh(aqm[r]);
          float sig_q = __expf(aql[r]);
          float dm = mu_q - mu_p;
          kacc += __logf(sig_p + 1e-6f) - __logf(sig_q + 1e-6f) - 0.5f
                + 0.5f*(dm*dm + sig_q*sig_q)/(sig_p*sig_p + 1e-6f);
        }
      }
      if (lane == 0)
        __hip_atomic_store(&flags[wg], t+1, __ATOMIC_RELEASE, __HIP_MEMORY_SCOPE_AGENT);
    }
  }
  if (isKL){
    #pragma unroll
    for (int s=32; s>0; s>>=1) kacc += __shfl_xor(kacc, s, 64);
    if (lane == 0) atomicAdd(dout + (size_t)BTD, kacc * (1e-3f/64.f));
  }
}

extern "C" void kernel_launch(void* const* d_in, const int* in_sizes, int n_in,
                              void* d_out, int out_size, void* d_ws, size_t ws_size,
                              hipStream_t stream){
  const float* hd        = (const float*)d_in[0];
  const float* A         = (const float*)d_in[1];
  const float* noise     = (const float*)d_in[2];
  const float* Wd        = (const float*)d_in[3];
  const float* Wz        = (const float*)d_in[4];
  const float* Wdz       = (const float*)d_in[5];
  const float* Whd       = (const float*)d_in[6];
  const float* bias      = (const float*)d_in[7];
  const float* init_h    = (const float*)d_in[8];
  const float* init_h_mu = (const float*)d_in[9];
  float* dout = (float*)d_out;

  char* ws = (char*)d_ws;
  unsigned short* hd_bf = (unsigned short*)(ws);                      // 33,554,432 B
  unsigned short* z_bf  = (unsigned short*)(ws + 33554432u);          //  4,194,304 B
  unsigned short* Wu    = (unsigned short*)(ws + 37748736u);          //    589,824 B
  unsigned short* Wp    = (unsigned short*)(ws + 38338560u);          //    655,360 B
  unsigned short* dcomm = (unsigned short*)(ws + 38993920u);          //     65,536 B
  int*            flags = (int*)          (ws + 39059456u);           //         80 B

  prep_hd_k  <<<2048, 256, 0, stream>>>(hd, hd_bf);
  prep_misc_k<<<1024, 256, 0, stream>>>(A, noise, Wd, Wz, Wdz, Whd, init_h,
                                        z_bf, Wu, Wp, dcomm, flags);
  wnll_k     <<<1,    256, 0, stream>>>(init_h, init_h_mu, dout);
  gemm_u_k   <<<1024, 256, 0, stream>>>(hd_bf, z_bf, Wu, bias, dout);
  recur_k    <<<20,    64, 0, stream>>>(dout, A, init_h, Wp, dcomm, flags);
}

// Round 2
// 7078.353 us; speedup vs baseline: 1.1862x; 1.1862x over previous
//
#include <hip/hip_runtime.h>

typedef float f32x4  __attribute__((ext_vector_type(4)));
typedef float f32x16 __attribute__((ext_vector_type(16)));
typedef short short8 __attribute__((ext_vector_type(8)));

#define TT 1024
#define DD 512
#define BTD (32u*1024u*512u)

__device__ __forceinline__ unsigned short f2bf(float f){
  unsigned int u = __float_as_uint(f);
  u += 0x7FFFu + ((u >> 16) & 1u);          // round-to-nearest-even
  return (unsigned short)(u >> 16);
}
__device__ __forceinline__ float fast_tanh(float x){
  float ax = fabsf(x);
  float e  = __expf(2.0f*ax);
  float r  = 1.0f - 2.0f/(e + 1.0f);
  return x < 0.f ? -r : r;
}

// ---------------- prep: hd -> bf16 ----------------
__global__ void prep_hd_k(const float* __restrict__ hd, unsigned short* __restrict__ out){
  const unsigned n4 = 16777216u/4u;
  for (unsigned i = blockIdx.x*blockDim.x + threadIdx.x; i < n4; i += gridDim.x*blockDim.x){
    f32x4 v = *reinterpret_cast<const f32x4*>(hd + 4u*(size_t)i);
    uint2 o;
    o.x = (unsigned)f2bf(v[0]) | ((unsigned)f2bf(v[1])<<16);
    o.y = (unsigned)f2bf(v[2]) | ((unsigned)f2bf(v[3])<<16);
    *reinterpret_cast<uint2*>(out + 4u*(size_t)i) = o;
  }
}

// ---------------- prep: z, packed weights, d_init, flags ----------------
__global__ void prep_misc_k(const float* __restrict__ A, const float* __restrict__ noise,
                            const float* __restrict__ Wd, const float* __restrict__ Wz,
                            const float* __restrict__ Wdz, const float* __restrict__ Whd,
                            const float* __restrict__ init_h,
                            unsigned short* __restrict__ zbf, unsigned short* __restrict__ Wu,
                            unsigned short* __restrict__ Wp, unsigned short* __restrict__ dcomm,
                            int* __restrict__ flags){
  const unsigned NZ = 2097152u, NWU = 294912u, NWP = 327680u, ND = 16384u;
  const unsigned NT = NZ + NWU + NWP + ND + 32u;
  for (unsigned i = blockIdx.x*blockDim.x + threadIdx.x; i < NT; i += gridDim.x*blockDim.x){
    if (i < NZ){                                   // z = tanh(mu_in_q) + noise*exp(ln_q)
      unsigned m = i >> 6, zi = i & 63u;
      float muin = A[(size_t)m*128u + zi];
      float ln   = A[(size_t)m*128u + 64u + zi];
      zbf[i] = f2bf(fast_tanh(muin) + noise[i]*__expf(ln));
    } else if (i < NZ+NWU){                        // Wu[c][kk]: [Whd | Wz], [512][576]
      unsigned j = i - NZ;
      unsigned c = j / 576u, kk = j - c*576u;
      float v = (kk < 512u) ? Whd[(size_t)c*512u + kk] : Wz[(size_t)c*64u + (kk-512u)];
      Wu[j] = f2bf(v);
    } else if (i < NZ+NWU+NWP){                    // Wp[c][k]: [Wd | Wdz interleaved], [640][512]
      unsigned j = i - (NZ+NWU);
      unsigned c = j >> 9, k = j & 511u;
      float v;
      if (c < 512u) v = Wd[(size_t)c*512u + k];
      else {
        unsigned jj = c - 512u, g = jj >> 5, w = jj & 31u;
        unsigned z = g*16u + (w & 15u), half = w >> 4;
        v = Wdz[(size_t)(half*64u + z)*512u + k];
      }
      Wp[j] = f2bf(v);
    } else if (i < NZ+NWU+NWP+ND){                 // d_{-1} = tanh(init_h) into ring slot 2
      unsigned j = i - (NZ+NWU+NWP);
      dcomm[2u*16384u + j] = f2bf(fast_tanh(init_h[j]));
    } else {
      unsigned j = i - (NZ+NWU+NWP+ND);
      if (j < 20u) flags[j] = 0;
    }
  }
}

// ---------------- wnll_init_h -> d_out[BTD] ----------------
__global__ void wnll_k(const float* __restrict__ init_h, const float* __restrict__ mu,
                       float* __restrict__ dout){
  __shared__ float red[256];
  float s = 0.f;
  for (unsigned i = threadIdx.x; i < 16384u; i += 256u){
    float x = init_h[i] - mu[i & 511u];
    s += 0.5f*x*x;
  }
  red[threadIdx.x] = s; __syncthreads();
  for (int st = 128; st > 0; st >>= 1){
    if ((int)threadIdx.x < st) red[threadIdx.x] += red[threadIdx.x + st];
    __syncthreads();
  }
  if (threadIdx.x == 0){
    float nll = (red[0] + 16384.0f*0.91893853320467274f) / 512.0f;
    dout[(size_t)BTD] = 1e-3f * nll;
  }
}

// ---------------- U = (X @ Wu^T + bias)/tau  into d_out ----------------
__global__ __launch_bounds__(256) void gemm_u_k(
    const unsigned short* __restrict__ Xhd,   // [32768][512] bf16
    const unsigned short* __restrict__ Xz,    // [32768][64]  bf16
    const unsigned short* __restrict__ Wu,    // [512][576]   bf16
    const float* __restrict__ bias,
    float* __restrict__ dout)                 // [32768][512] f32
{
  __shared__ __align__(16) unsigned short Xs[128][40];   // 128m x 32k (+8 pad)
  __shared__ __align__(16) unsigned short Ws[128][40];   // 128c x 32k
  const int bm = blockIdx.x >> 2;
  const int bn = blockIdx.x & 3;
  const int tid = threadIdx.x;
  const int lane = tid & 63;
  const int wv = tid >> 6;
  const int m0 = (wv >> 1) * 64, c0 = (wv & 1) * 64;
  f32x4 acc[4][4];
  #pragma unroll
  for (int i=0;i<4;++i)
    #pragma unroll
    for (int j=0;j<4;++j)
      #pragma unroll
      for (int r=0;r<4;++r) acc[i][j][r] = 0.f;

  const int sm = tid >> 1;
  const int sk = (tid & 1) * 16;
  for (int kt = 0; kt < 18; ++kt){
    __syncthreads();
    {
      int mg = bm*128 + sm;
      const unsigned short* src = (kt < 16)
          ? (Xhd + (size_t)mg*512u + (unsigned)(kt*32 + sk))
          : (Xz  + (size_t)mg*64u  + (unsigned)((kt-16)*32 + sk));
      uint4 v0 = *reinterpret_cast<const uint4*>(src);
      uint4 v1 = *reinterpret_cast<const uint4*>(src + 8);
      *reinterpret_cast<uint4*>(&Xs[sm][sk])   = v0;
      *reinterpret_cast<uint4*>(&Xs[sm][sk+8]) = v1;
      int cg = bn*128 + sm;
      const unsigned short* wsrc = Wu + (size_t)cg*576u + (unsigned)(kt*32 + sk);
      uint4 w0 = *reinterpret_cast<const uint4*>(wsrc);
      uint4 w1 = *reinterpret_cast<const uint4*>(wsrc + 8);
      *reinterpret_cast<uint4*>(&Ws[sm][sk])   = w0;
      *reinterpret_cast<uint4*>(&Ws[sm][sk+8]) = w1;
    }
    __syncthreads();
    short8 af[4], bf[4];
    #pragma unroll
    for (int i=0;i<4;++i)
      af[i] = *reinterpret_cast<const short8*>(&Xs[m0 + i*16 + (lane&15)][(lane>>4)*8]);
    #pragma unroll
    for (int j=0;j<4;++j)
      bf[j] = *reinterpret_cast<const short8*>(&Ws[c0 + j*16 + (lane&15)][(lane>>4)*8]);
    #pragma unroll
    for (int i=0;i<4;++i)
      #pragma unroll
      for (int j=0;j<4;++j)
        acc[i][j] = __builtin_amdgcn_mfma_f32_16x16x32_bf16(af[i], bf[j], acc[i][j], 0, 0, 0);
  }
  #pragma unroll
  for (int j=0;j<4;++j){
    int cg = bn*128 + c0 + j*16 + (lane&15);
    float bia  = bias[cg];
    float itau = (cg < 256) ? 0.25f : 0.5f;
    #pragma unroll
    for (int i=0;i<4;++i){
      int mbase = bm*128 + m0 + i*16 + (lane>>4)*4;
      #pragma unroll
      for (int r=0;r<4;++r)
        dout[(size_t)(mbase + r)*512u + cg] = (acc[i][j][r] + bia) * itau;
    }
  }
}

// ---------------- persistent serial recurrence: 20 WGs x 1 wave ----------------
// WG 0..15: D columns [32*wg, 32*wg+32);  WG 16..19: prior columns + KL.
// Sync fabric: system-scope (sc0 sc1) write-through stores + cache-bypass loads,
// manual vmcnt(0) release, 3-slot dcomm ring, no acquire fences.
__global__ __launch_bounds__(64,1) void recur_k(
    float* __restrict__ dout, const float* __restrict__ A, const float* __restrict__ init_h,
    const unsigned short* __restrict__ Wp, unsigned short* __restrict__ dcomm,
    int* __restrict__ flags)
{
  const int wg   = blockIdx.x;
  const int lane = threadIdx.x;
  const bool isKL = (wg >= 16);
  const int col   = wg*32 + (lane & 31);      // packed column (0..639)
  const int khalf = (lane >> 5) * 8;          // k sub-offset of this lane half
  const int bof   = (lane >> 5) * 4;          // row offset in C-layout

  // weights resident in VGPRs: 32 fragments of 8 bf16
  short8 wfrag[32];
  #pragma unroll
  for (int kc = 0; kc < 32; ++kc)
    wfrag[kc] = *reinterpret_cast<const short8*>(Wp + (size_t)col*512u + (unsigned)(kc*16 + khalf));

  const float dec  = (col < 256) ? 0.75f : 0.5f;
  const float itau = (col < 256) ? 0.25f : 0.5f;

  float h[16];
  if (!isKL){
    #pragma unroll
    for (int r=0;r<16;++r){
      int b = (r&3) + 8*(r>>2) + bof;
      h[r] = init_h[b*512 + col];
    }
  }
  const int  zidx   = (wg - 16)*16 + (lane & 15);
  const bool muLane = ((lane & 16) == 0);
  float kacc = 0.f;

  // per-lane byte base inside a dcomm slot (row-major [32][512] bf16)
  const unsigned laneoff_ull = (unsigned)(((lane & 31)*512 + khalf) >> 2); // /4 shorts per ull

  // prefetch step-0 recurrence-independent data
  float u[16], aqm[16], aql[16];
  if (!isKL){
    #pragma unroll
    for (int r=0;r<16;++r){
      int b = (r&3) + 8*(r>>2) + bof;
      u[r] = dout[((size_t)b*TT + 0)*DD + col];
    }
  } else {
    #pragma unroll
    for (int r=0;r<16;++r){
      int b = (r&3) + 8*(r>>2) + bof;
      const float* ap = A + ((size_t)b*TT + 0)*128u;
      aqm[r] = ap[zidx]; aql[r] = ap[64 + zidx];
    }
  }

  int rs = 2, wsl = 0;   // read slot (t-1)%3, write slot t%3
  union U16 { unsigned long long q[2]; short8 s; };

  for (int t = 0; t < TT; ++t){
    // lockstep: D lanes need flag>=t, KL lanes need flag>=t-1 (ring gives 1-step slack)
    if (t > 0){
      for (;;){
        int ok = 1;
        if (lane < 20){
          int f = __hip_atomic_load(&flags[lane], __ATOMIC_RELAXED, __HIP_MEMORY_SCOPE_SYSTEM);
          ok = (f >= ((lane < 16) ? t : t-1));
        }
        if (__all(ok)) break;
        __builtin_amdgcn_s_sleep(1);
      }
      asm volatile("" ::: "memory");
    }

    // load d_{t-1} fragments from ring slot rs (cache-bypass -> coherence point)
    const unsigned long long* dsq =
        reinterpret_cast<const unsigned long long*>(dcomm + rs*16384) + laneoff_ull;
    U16 fr[32];
    #pragma unroll
    for (int j=0;j<32;++j){
      fr[j].q[0] = __hip_atomic_load(dsq + j*4 + 0, __ATOMIC_RELAXED, __HIP_MEMORY_SCOPE_SYSTEM);
      fr[j].q[1] = __hip_atomic_load(dsq + j*4 + 1, __ATOMIC_RELAXED, __HIP_MEMORY_SCOPE_SYSTEM);
    }

    if (isKL){
      // publish "reads done" as early as possible: KL stays off the critical path
      asm volatile("s_waitcnt vmcnt(0)" ::: "memory");
      if (lane == 0)
        __hip_atomic_store(&flags[wg], t+1, __ATOMIC_RELAXED, __HIP_MEMORY_SCOPE_SYSTEM);
    }

    // P = d_{t-1} @ W_slice   (two interleaved MFMA chains)
    f32x16 acc0, acc1;
    #pragma unroll
    for (int q=0;q<16;++q){ acc0[q]=0.f; acc1[q]=0.f; }
    #pragma unroll
    for (int kc=0;kc<16;++kc){
      acc0 = __builtin_amdgcn_mfma_f32_32x32x16_bf16(fr[2*kc  ].s, wfrag[2*kc  ], acc0, 0, 0, 0);
      acc1 = __builtin_amdgcn_mfma_f32_32x32x16_bf16(fr[2*kc+1].s, wfrag[2*kc+1], acc1, 0, 0, 0);
    }

    if (!isKL){
      float dv[16];
      #pragma unroll
      for (int r=0;r<16;++r){
        float P = acc0[r] + acc1[r];
        h[r]  = dec*h[r] + P*itau + u[r];
        dv[r] = fast_tanh(h[r]);
      }
      // bf16 d_comm into write slot (paired dword write-through stores)
      unsigned short* dslot = dcomm + wsl*16384;
      #pragma unroll
      for (int r=0;r<16;++r){
        float nb = __shfl_xor(dv[r], 1, 64);
        unsigned short mb = f2bf(dv[r]), ob = f2bf(nb);
        unsigned int dw = (lane & 1) ? (((unsigned)mb<<16) | ob) : (((unsigned)ob<<16) | mb);
        if ((lane & 1) == ((r < 8) ? 0 : 1)){
          int b = (r&3) + 8*(r>>2) + bof;
          unsigned int* dst = reinterpret_cast<unsigned int*>(dslot + b*512 + (col & ~1));
          __hip_atomic_store(dst, dw, __ATOMIC_RELAXED, __HIP_MEMORY_SCOPE_SYSTEM);
        }
      }
      // manual release: drain write-throughs, then flag
      asm volatile("s_waitcnt vmcnt(0)" ::: "memory");
      if (lane == 0)
        __hip_atomic_store(&flags[wg], t+1, __ATOMIC_RELAXED, __HIP_MEMORY_SCOPE_SYSTEM);
      // off-critical-path: d_seq output + next-step u prefetch
      #pragma unroll
      for (int r=0;r<16;++r){
        int b = (r&3) + 8*(r>>2) + bof;
        __hip_atomic_store(&dout[((size_t)b*TT + t)*DD + col], dv[r],
                           __ATOMIC_RELAXED, __HIP_MEMORY_SCOPE_SYSTEM);
      }
      if (t+1 < TT){
        #pragma unroll
        for (int r=0;r<16;++r){
          int b = (r&3) + 8*(r>>2) + bof;
          u[r] = dout[((size_t)b*TT + (t+1))*DD + col];
        }
      }
    } else {
      // prior + KL (flag already published)
      #pragma unroll
      for (int r=0;r<16;++r){
        float P = acc0[r] + acc1[r];
        if (t == 0) P = 0.f;                       // in_p0 is zeros
        float other = __shfl_xor(P, 16, 64);       // pair mu <-> ln lanes
        if (muLane){
          float mu_p  = fast_tanh(P);
          float sig_p = __expf(other);
          float mu_q  = fast_tanh(aqm[r]);
          float sig_q = __expf(aql[r]);
          float dm = mu_q - mu_p;
          kacc += __logf(sig_p + 1e-6f) - __logf(sig_q + 1e-6f) - 0.5f
                + 0.5f*(dm*dm + sig_q*sig_q)/(sig_p*sig_p + 1e-6f);
        }
      }
      if (t+1 < TT){
        #pragma unroll
        for (int r=0;r<16;++r){
          int b = (r&3) + 8*(r>>2) + bof;
          const float* ap = A + ((size_t)b*TT + (t+1))*128u;
          aqm[r] = ap[zidx]; aql[r] = ap[64 + zidx];
        }
      }
    }
    rs = wsl;
    wsl = (wsl == 2) ? 0 : wsl + 1;
  }
  if (isKL){
    #pragma unroll
    for (int s=32; s>0; s>>=1) kacc += __shfl_xor(kacc, s, 64);
    if (lane == 0) atomicAdd(dout + (size_t)BTD, kacc * (1e-3f/64.f));
  }
}

extern "C" void kernel_launch(void* const* d_in, const int* in_sizes, int n_in,
                              void* d_out, int out_size, void* d_ws, size_t ws_size,
                              hipStream_t stream){
  const float* hd        = (const float*)d_in[0];
  const float* A         = (const float*)d_in[1];
  const float* noise     = (const float*)d_in[2];
  const float* Wd        = (const float*)d_in[3];
  const float* Wz        = (const float*)d_in[4];
  const float* Wdz       = (const float*)d_in[5];
  const float* Whd       = (const float*)d_in[6];
  const float* bias      = (const float*)d_in[7];
  const float* init_h    = (const float*)d_in[8];
  const float* init_h_mu = (const float*)d_in[9];
  float* dout = (float*)d_out;

  char* ws = (char*)d_ws;
  unsigned short* hd_bf = (unsigned short*)(ws);                      // 33,554,432 B
  unsigned short* z_bf  = (unsigned short*)(ws + 33554432u);          //  4,194,304 B
  unsigned short* Wu    = (unsigned short*)(ws + 37748736u);          //    589,824 B
  unsigned short* Wp    = (unsigned short*)(ws + 38338560u);          //    655,360 B
  unsigned short* dcomm = (unsigned short*)(ws + 38993920u);          //    196,608 B (3 ring slots)
  int*            flags = (int*)          (ws + 39190528u);           //         80 B

  prep_hd_k  <<<2048, 256, 0, stream>>>(hd, hd_bf);
  prep_misc_k<<<1024, 256, 0, stream>>>(A, noise, Wd, Wz, Wdz, Whd, init_h,
                                        z_bf, Wu, Wp, dcomm, flags);
  wnll_k     <<<1,    256, 0, stream>>>(init_h, init_h_mu, dout);
  gemm_u_k   <<<1024, 256, 0, stream>>>(hd_bf, z_bf, Wu, bias, dout);
  recur_k    <<<20,    64, 0, stream>>>(dout, A, init_h, Wp, dcomm, flags);
}

// Round 4
// 5412.749 us; speedup vs baseline: 1.5512x; 1.3077x over previous
//
#include <hip/hip_runtime.h>

typedef float f32x4  __attribute__((ext_vector_type(4)));
typedef float f32x16 __attribute__((ext_vector_type(16)));
typedef short short8 __attribute__((ext_vector_type(8)));
typedef int   intx4  __attribute__((ext_vector_type(4)));

#define TT 1024
#define DD 512
#define BTD (32u*1024u*512u)

__device__ __forceinline__ unsigned short f2bf(float f){
  unsigned int u = __float_as_uint(f);
  u += 0x7FFFu + ((u >> 16) & 1u);          // round-to-nearest-even
  return (unsigned short)(u >> 16);
}
__device__ __forceinline__ float fast_tanh(float x){
  float ax = fabsf(x);
  float e  = __expf(2.0f*ax);
  float r  = 1.0f - 2.0f/(e + 1.0f);
  return x < 0.f ? -r : r;
}

// ---------------- prep: hd -> bf16 ----------------
__global__ void prep_hd_k(const float* __restrict__ hd, unsigned short* __restrict__ out){
  const unsigned n4 = 16777216u/4u;
  for (unsigned i = blockIdx.x*blockDim.x + threadIdx.x; i < n4; i += gridDim.x*blockDim.x){
    f32x4 v = *reinterpret_cast<const f32x4*>(hd + 4u*(size_t)i);
    uint2 o;
    o.x = (unsigned)f2bf(v[0]) | ((unsigned)f2bf(v[1])<<16);
    o.y = (unsigned)f2bf(v[2]) | ((unsigned)f2bf(v[3])<<16);
    *reinterpret_cast<uint2*>(out + 4u*(size_t)i) = o;
  }
}

// ---------------- prep: z, packed weights, d_init (fragment layout), flags ----------------
__global__ void prep_misc_k(const float* __restrict__ A, const float* __restrict__ noise,
                            const float* __restrict__ Wd, const float* __restrict__ Wz,
                            const float* __restrict__ Wdz, const float* __restrict__ Whd,
                            const float* __restrict__ init_h,
                            unsigned short* __restrict__ zbf, unsigned short* __restrict__ Wu,
                            unsigned short* __restrict__ Wp, unsigned short* __restrict__ dcomm,
                            int* __restrict__ flags){
  const unsigned NZ = 2097152u, NWU = 294912u, NWP = 327680u, ND = 16384u;
  const unsigned NT = NZ + NWU + NWP + ND + 32u;
  for (unsigned i = blockIdx.x*blockDim.x + threadIdx.x; i < NT; i += gridDim.x*blockDim.x){
    if (i < NZ){                                   // z = tanh(mu_in_q) + noise*exp(ln_q)
      unsigned m = i >> 6, zi = i & 63u;
      float muin = A[(size_t)m*128u + zi];
      float ln   = A[(size_t)m*128u + 64u + zi];
      zbf[i] = f2bf(fast_tanh(muin) + noise[i]*__expf(ln));
    } else if (i < NZ+NWU){                        // Wu[c][kk]: [Whd | Wz], [512][576]
      unsigned j = i - NZ;
      unsigned c = j / 576u, kk = j - c*576u;
      float v = (kk < 512u) ? Whd[(size_t)c*512u + kk] : Wz[(size_t)c*64u + (kk-512u)];
      Wu[j] = f2bf(v);
    } else if (i < NZ+NWU+NWP){                    // Wp[c][k]: [Wd | Wdz interleaved], [640][512]
      unsigned j = i - (NZ+NWU);
      unsigned c = j >> 9, k = j & 511u;
      float v;
      if (c < 512u) v = Wd[(size_t)c*512u + k];
      else {
        unsigned jj = c - 512u, g = jj >> 5, w = jj & 31u;
        unsigned z = g*16u + (w & 15u), half = w >> 4;
        v = Wdz[(size_t)(half*64u + z)*512u + k];
      }
      Wp[j] = f2bf(v);
    } else if (i < NZ+NWU+NWP+ND){                 // d_{-1} = tanh(init_h) -> slot 2, fragment layout
      unsigned j = i - (NZ+NWU+NWP);
      unsigned b = j >> 9, c = j & 511u;
      unsigned idx = ((c>>4)<<9) + (((c>>3)&1u)<<8) + (b<<3) + (c&7u);
      dcomm[2u*16384u + idx] = f2bf(fast_tanh(init_h[j]));
    } else {
      unsigned j = i - (NZ+NWU+NWP+ND);
      if (j < 32u) flags[j] = 0;
    }
  }
}

// ---------------- wnll_init_h -> d_out[BTD] ----------------
__global__ void wnll_k(const float* __restrict__ init_h, const float* __restrict__ mu,
                       float* __restrict__ dout){
  __shared__ float red[256];
  float s = 0.f;
  for (unsigned i = threadIdx.x; i < 16384u; i += 256u){
    float x = init_h[i] - mu[i & 511u];
    s += 0.5f*x*x;
  }
  red[threadIdx.x] = s; __syncthreads();
  for (int st = 128; st > 0; st >>= 1){
    if ((int)threadIdx.x < st) red[threadIdx.x] += red[threadIdx.x + st];
    __syncthreads();
  }
  if (threadIdx.x == 0){
    float nll = (red[0] + 16384.0f*0.91893853320467274f) / 512.0f;
    dout[(size_t)BTD] = 1e-3f * nll;
  }
}

// ---------------- U = (X @ Wu^T + bias)/tau  into d_out ----------------
__global__ __launch_bounds__(256) void gemm_u_k(
    const unsigned short* __restrict__ Xhd,   // [32768][512] bf16
    const unsigned short* __restrict__ Xz,    // [32768][64]  bf16
    const unsigned short* __restrict__ Wu,    // [512][576]   bf16
    const float* __restrict__ bias,
    float* __restrict__ dout)                 // [32768][512] f32
{
  __shared__ __align__(16) unsigned short Xs[128][40];
  __shared__ __align__(16) unsigned short Ws[128][40];
  const int bm = blockIdx.x >> 2;
  const int bn = blockIdx.x & 3;
  const int tid = threadIdx.x;
  const int lane = tid & 63;
  const int wv = tid >> 6;
  const int m0 = (wv >> 1) * 64, c0 = (wv & 1) * 64;
  f32x4 acc[4][4];
  #pragma unroll
  for (int i=0;i<4;++i)
    #pragma unroll
    for (int j=0;j<4;++j)
      #pragma unroll
      for (int r=0;r<4;++r) acc[i][j][r] = 0.f;

  const int sm = tid >> 1;
  const int sk = (tid & 1) * 16;
  for (int kt = 0; kt < 18; ++kt){
    __syncthreads();
    {
      int mg = bm*128 + sm;
      const unsigned short* src = (kt < 16)
          ? (Xhd + (size_t)mg*512u + (unsigned)(kt*32 + sk))
          : (Xz  + (size_t)mg*64u  + (unsigned)((kt-16)*32 + sk));
      uint4 v0 = *reinterpret_cast<const uint4*>(src);
      uint4 v1 = *reinterpret_cast<const uint4*>(src + 8);
      *reinterpret_cast<uint4*>(&Xs[sm][sk])   = v0;
      *reinterpret_cast<uint4*>(&Xs[sm][sk+8]) = v1;
      int cg = bn*128 + sm;
      const unsigned short* wsrc = Wu + (size_t)cg*576u + (unsigned)(kt*32 + sk);
      uint4 w0 = *reinterpret_cast<const uint4*>(wsrc);
      uint4 w1 = *reinterpret_cast<const uint4*>(wsrc + 8);
      *reinterpret_cast<uint4*>(&Ws[sm][sk])   = w0;
      *reinterpret_cast<uint4*>(&Ws[sm][sk+8]) = w1;
    }
    __syncthreads();
    short8 af[4], bf[4];
    #pragma unroll
    for (int i=0;i<4;++i)
      af[i] = *reinterpret_cast<const short8*>(&Xs[m0 + i*16 + (lane&15)][(lane>>4)*8]);
    #pragma unroll
    for (int j=0;j<4;++j)
      bf[j] = *reinterpret_cast<const short8*>(&Ws[c0 + j*16 + (lane&15)][(lane>>4)*8]);
    #pragma unroll
    for (int i=0;i<4;++i)
      #pragma unroll
      for (int j=0;j<4;++j)
        acc[i][j] = __builtin_amdgcn_mfma_f32_16x16x32_bf16(af[i], bf[j], acc[i][j], 0, 0, 0);
  }
  #pragma unroll
  for (int j=0;j<4;++j){
    int cg = bn*128 + c0 + j*16 + (lane&15);
    float bia  = bias[cg];
    float itau = (cg < 256) ? 0.25f : 0.5f;
    #pragma unroll
    for (int i=0;i<4;++i){
      int mbase = bm*128 + m0 + i*16 + (lane>>4)*4;
      #pragma unroll
      for (int r=0;r<4;++r)
        dout[(size_t)(mbase + r)*512u + cg] = (acc[i][j][r] + bia) * itau;
    }
  }
}

// ---------------- persistent serial recurrence: 20 WGs x 1 wave ----------------
// WG 0..15: D columns [32*wg, +32);  WG 16..19: prior columns + KL.
// Fabric: system-scope (sc0 sc1) coalesced b128 loads/stores of a fragment-layout
// dcomm ring (3 slots), manual vmcnt(0) release, system-scope flags. (round-2
// fabric, proven; round-3 XCD election removed after hang.)
__global__ __launch_bounds__(64,1) void recur_k(
    float* __restrict__ dout, const float* __restrict__ A, const float* __restrict__ init_h,
    const unsigned short* __restrict__ Wp, unsigned short* __restrict__ dcomm,
    int* __restrict__ flags)
{
  __shared__ __align__(16) unsigned short tl[32][40];   // transpose block
  const int wg   = blockIdx.x;
  const int lane = threadIdx.x;
  const bool isKL = (wg >= 16);
  const int pc    = wg*32 + (lane & 31);      // packed column 0..639
  const int khalf = (lane >> 5) * 8;
  const int bof   = (lane >> 5) * 4;

  // weights resident in VGPRs: 32 B-fragments of 8 bf16
  short8 wfrag[32];
  #pragma unroll
  for (int kc = 0; kc < 32; ++kc)
    wfrag[kc] = *reinterpret_cast<const short8*>(Wp + (size_t)pc*512u + (unsigned)(kc*16 + khalf));

  const float dec  = (pc < 256) ? 0.75f : 0.5f;
  const float itau = (pc < 256) ? 0.25f : 0.5f;

  float h[16];
  if (!isKL){
    #pragma unroll
    for (int r=0;r<16;++r){
      int b = (r&3) + 8*(r>>2) + bof;
      h[r] = init_h[b*512 + pc];
    }
  }
  const int  zidx   = (wg - 16)*16 + (lane & 15);
  const bool muLane = ((lane & 16) == 0);
  float kacc = 0.f;

  // step-0 recurrence-independent prefetch
  float u[16], aqm[16], aql[16];
  if (!isKL){
    #pragma unroll
    for (int r=0;r<16;++r){
      int b = (r&3) + 8*(r>>2) + bof;
      u[r] = dout[((size_t)b*TT + 0)*DD + pc];
    }
  } else {
    #pragma unroll
    for (int r=0;r<16;++r){
      int b = (r&3) + 8*(r>>2) + bof;
      const float* ap = A + ((size_t)b*TT + 0)*128u;
      aqm[r] = ap[zidx]; aql[r] = ap[64 + zidx];
    }
  }

  const int* fp  = flags + ((lane < 20) ? lane : 0);
  const int thro = (lane >= 16 && lane < 20) ? -1 : 0;
  int* const myflag = &flags[wg];

  int rs = 2, wsl = 0;
  union CV { intx4 i; short8 s; };

  for (int t = 0; t < TT; ++t){
    // lockstep: worker flags >= t, KL flags >= t-1 (3-slot ring gives KL slack)
    if (t > 0){
      const int thr = t + thro;
      for (;;){
        int f;
        asm volatile("global_load_dword %0, %1, off sc0 sc1\n\t"
                     "s_waitcnt vmcnt(0)"
                     : "=&v"(f) : "v"(fp) : "memory");
        if (__all(f >= thr)) break;
      }
    }

    // coalesced fragment gather of d_{t-1} (system scope, straight to coherence point)
    const char* base = (const char*)dcomm + rs*32768 + lane*16;
    intx4 fi[32];
    #pragma unroll
    for (int g = 0; g < 8; ++g){
      const char* bp = base + g*4096;
      asm volatile(
        "global_load_dwordx4 %0, %4, off sc0 sc1\n\t"
        "global_load_dwordx4 %1, %4, off offset:1024 sc0 sc1\n\t"
        "global_load_dwordx4 %2, %4, off offset:2048 sc0 sc1\n\t"
        "global_load_dwordx4 %3, %4, off offset:3072 sc0 sc1"
        : "=&v"(fi[4*g]), "=&v"(fi[4*g+1]), "=&v"(fi[4*g+2]), "=&v"(fi[4*g+3])
        : "v"(bp) : "memory");
    }
    asm volatile("s_waitcnt vmcnt(0)" ::: "memory");
    __builtin_amdgcn_sched_barrier(0);

    if (isKL){
      // publish "reads done" early: KL drops off the critical path
      if (lane == 0){
        int val = t + 1;
        asm volatile("global_store_dword %0, %1, off sc0 sc1"
                     :: "v"(myflag), "v"(val) : "memory");
      }
    }

    // P = d_{t-1} @ W_slice  (two interleaved MFMA chains)
    f32x16 acc0, acc1;
    #pragma unroll
    for (int q=0;q<16;++q){ acc0[q]=0.f; acc1[q]=0.f; }
    #pragma unroll
    for (int kc=0;kc<16;++kc){
      CV c0, c1; c0.i = fi[2*kc]; c1.i = fi[2*kc+1];
      acc0 = __builtin_amdgcn_mfma_f32_32x32x16_bf16(c0.s, wfrag[2*kc  ], acc0, 0, 0, 0);
      acc1 = __builtin_amdgcn_mfma_f32_32x32x16_bf16(c1.s, wfrag[2*kc+1], acc1, 0, 0, 0);
    }

    if (!isKL){
      float dv[16];
      #pragma unroll
      for (int r=0;r<16;++r){
        float P = acc0[r] + acc1[r];
        h[r]  = dec*h[r] + P*itau + u[r];
        dv[r] = fast_tanh(h[r]);
      }
      // in-wave transpose via LDS: tl[batch][local col]
      #pragma unroll
      for (int r=0;r<16;++r){
        int b = (r&3) + 8*(r>>2) + bof;
        tl[b][lane & 31] = f2bf(dv[r]);
      }
      // two coalesced b128 system-scope stores into fragment-layout dcomm
      {
        unsigned short* ds = dcomm + wsl*16384 + (2*wg)*512 + lane*8;
        short8 s0 = *reinterpret_cast<const short8*>(&tl[lane & 31][khalf]);
        short8 s1 = *reinterpret_cast<const short8*>(&tl[lane & 31][16 + khalf]);
        asm volatile("global_store_dwordx4 %0, %2, off sc0 sc1\n\t"
                     "global_store_dwordx4 %1, %3, off sc0 sc1"
                     :: "v"(ds), "v"(ds + 512), "v"(s0), "v"(s1) : "memory");
      }
      // release: drain stores to coherence point, then publish flag
      asm volatile("s_waitcnt vmcnt(0)" ::: "memory");
      if (lane == 0){
        int val = t + 1;
        asm volatile("global_store_dword %0, %1, off sc0 sc1"
                     :: "v"(myflag), "v"(val) : "memory");
      }
      // off-critical-path: d_seq output (plain cached) + next-step u prefetch
      #pragma unroll
      for (int r=0;r<16;++r){
        int b = (r&3) + 8*(r>>2) + bof;
        dout[((size_t)b*TT + t)*DD + pc] = dv[r];
      }
      if (t+1 < TT){
        #pragma unroll
        for (int r=0;r<16;++r){
          int b = (r&3) + 8*(r>>2) + bof;
          u[r] = dout[((size_t)b*TT + (t+1))*DD + pc];
        }
      }
    } else {
      // prior + KL (flag already published)
      #pragma unroll
      for (int r=0;r<16;++r){
        float P = acc0[r] + acc1[r];
        if (t == 0) P = 0.f;                       // in_p0 is zeros
        float other = __shfl_xor(P, 16, 64);       // pair mu <-> ln lanes
        if (muLane){
          float mu_p  = fast_tanh(P);
          float sig_p = __expf(other);
          float mu_q  = fast_tanh(aqm[r]);
          float sig_q = __expf(aql[r]);
          float dm = mu_q - mu_p;
          kacc += __logf(sig_p + 1e-6f) - __logf(sig_q + 1e-6f) - 0.5f
                + 0.5f*(dm*dm + sig_q*sig_q)/(sig_p*sig_p + 1e-6f);
        }
      }
      if (t+1 < TT){
        #pragma unroll
        for (int r=0;r<16;++r){
          int b = (r&3) + 8*(r>>2) + bof;
          const float* ap = A + ((size_t)b*TT + (t+1))*128u;
          aqm[r] = ap[zidx]; aql[r] = ap[64 + zidx];
        }
      }
    }
    rs = wsl;
    wsl = (wsl == 2) ? 0 : wsl + 1;
  }
  if (isKL){
    #pragma unroll
    for (int s=32; s>0; s>>=1) kacc += __shfl_xor(kacc, s, 64);
    if (lane == 0) atomicAdd(dout + (size_t)BTD, kacc * (1e-3f/64.f));
  }
}

extern "C" void kernel_launch(void* const* d_in, const int* in_sizes, int n_in,
                              void* d_out, int out_size, void* d_ws, size_t ws_size,
                              hipStream_t stream){
  const float* hd        = (const float*)d_in[0];
  const float* A         = (const float*)d_in[1];
  const float* noise     = (const float*)d_in[2];
  const float* Wd        = (const float*)d_in[3];
  const float* Wz        = (const float*)d_in[4];
  const float* Wdz       = (const float*)d_in[5];
  const float* Whd       = (const float*)d_in[6];
  const float* bias      = (const float*)d_in[7];
  const float* init_h    = (const float*)d_in[8];
  const float* init_h_mu = (const float*)d_in[9];
  float* dout = (float*)d_out;

  char* ws = (char*)d_ws;
  unsigned short* hd_bf = (unsigned short*)(ws);                      // 33,554,432 B
  unsigned short* z_bf  = (unsigned short*)(ws + 33554432u);          //  4,194,304 B
  unsigned short* Wu    = (unsigned short*)(ws + 37748736u);          //    589,824 B
  unsigned short* Wp    = (unsigned short*)(ws + 38338560u);          //    655,360 B
  unsigned short* dcomm = (unsigned short*)(ws + 38993920u);          //    196,608 B (3 ring slots, frag layout)
  int*            flags = (int*)          (ws + 39190528u);           //        128 B

  prep_hd_k  <<<2048, 256, 0, stream>>>(hd, hd_bf);
  prep_misc_k<<<1024, 256, 0, stream>>>(A, noise, Wd, Wz, Wdz, Whd, init_h,
                                        z_bf, Wu, Wp, dcomm, flags);
  wnll_k     <<<1,    256, 0, stream>>>(init_h, init_h_mu, dout);
  gemm_u_k   <<<1024, 256, 0, stream>>>(hd_bf, z_bf, Wu, bias, dout);
  recur_k    <<<20,    64, 0, stream>>>(dout, A, init_h, Wp, dcomm, flags);
}